// Round 1
// baseline (25618.808 us; speedup 1.0000x reference)
//
#include <hip/hip_runtime.h>

// ---------------------------------------------------------------------------
// R-Net forward on MI355X. fp32 baseline.
// Dimensions (fixed by the problem):
//   P=256 passage len, Q=48 question len, B=16 batch, E=300, H=128
//   D = E+2H = 556, 2H=256, 3H=384, 4H=512
// Structure:
//   1. Pre-transpose recurrent weights to k-major (one batched kernel).
//   2. Big GEMMs for all state-independent projections.
//   3. Sequential recurrence kernels: one workgroup per independent chain,
//      all T steps inside the kernel with __syncthreads between stages.
// ---------------------------------------------------------------------------

#define PP 256
#define QQ 48
#define BB 16

__device__ __forceinline__ float fast_rcp(float x) { return __builtin_amdgcn_rcpf(x); }
__device__ __forceinline__ float tanh_f(float x) {
  // tanh(x) = 1 - 2/(1+e^{2x}); saturates correctly via exp overflow/underflow
  float e = __expf(2.0f * x);
  return 1.0f - 2.0f * fast_rcp(1.0f + e);
}
__device__ __forceinline__ float sigm_f(float x) {
  return fast_rcp(1.0f + __expf(-x));
}

// ---------------------------------------------------------------------------
// Generic C[M,N] = A[M,K] @ W[N,K]^T + bias.  64x64 tiles, BK=16, 256 thr.
// M,N must be multiples of 64 (true for all uses); K multiple of 4.
// ---------------------------------------------------------------------------
__global__ __launch_bounds__(256) void gemm_nt(
    const float* __restrict__ A, int lda,
    const float* __restrict__ W, int ldw,
    const float* __restrict__ bias,
    float* __restrict__ C, int ldc, int K) {
  __shared__ float As[64][17];
  __shared__ float Ws[64][17];
  int tid = threadIdx.x;
  int m0 = blockIdx.x * 64, n0 = blockIdx.y * 64;
  int lr = tid >> 2, lq = (tid & 3) * 4;
  int tr = tid >> 4, tc = tid & 15;
  float acc[4][4] = {};
  for (int k0 = 0; k0 < K; k0 += 16) {
    float4 av = {0,0,0,0}, wv = {0,0,0,0};
    if (k0 + lq < K) {
      av = *(const float4*)&A[(size_t)(m0 + lr) * lda + k0 + lq];
      wv = *(const float4*)&W[(size_t)(n0 + lr) * ldw + k0 + lq];
    }
    __syncthreads();
    As[lr][lq+0] = av.x; As[lr][lq+1] = av.y; As[lr][lq+2] = av.z; As[lr][lq+3] = av.w;
    Ws[lr][lq+0] = wv.x; Ws[lr][lq+1] = wv.y; Ws[lr][lq+2] = wv.z; Ws[lr][lq+3] = wv.w;
    __syncthreads();
#pragma unroll
    for (int kk = 0; kk < 16; ++kk) {
      float a4[4], b4[4];
#pragma unroll
      for (int i = 0; i < 4; ++i) a4[i] = As[tr*4+i][kk];
#pragma unroll
      for (int j = 0; j < 4; ++j) b4[j] = Ws[tc*4+j][kk];
#pragma unroll
      for (int i = 0; i < 4; ++i)
#pragma unroll
        for (int j = 0; j < 4; ++j) acc[i][j] += a4[i] * b4[j];
    }
  }
#pragma unroll
  for (int i = 0; i < 4; ++i) {
    int m = m0 + tr*4 + i;
#pragma unroll
    for (int j = 0; j < 4; ++j) {
      int n = n0 + tc*4 + j;
      C[(size_t)m * ldc + n] = acc[i][j] + (bias ? bias[n] : 0.0f);
    }
  }
}

// ---------------------------------------------------------------------------
// Batched weight transposes: dst[c*R + r] = src[r*ld + off + c]
// ---------------------------------------------------------------------------
struct TDesc { const float* src; float* dst; int R, C, ld, off; };
struct TDescs { TDesc d[16]; };

__global__ __launch_bounds__(256) void transpose_many(TDescs ds) {
  TDesc d = ds.d[blockIdx.y];
  int idx = blockIdx.x * 256 + threadIdx.x;
  if (idx < d.R * d.C) {
    int r = idx / d.C, cc = idx % d.C;
    d.dst[(size_t)cc * d.R + r] = d.src[(size_t)r * d.ld + d.off + cc];
  }
}

__global__ __launch_bounds__(256) void transpose_one(
    const float* __restrict__ src, float* __restrict__ dst, int R, int C) {
  int idx = blockIdx.x * 256 + threadIdx.x;
  if (idx < R * C) {
    int r = idx / C, cc = idx % C;
    dst[(size_t)cc * R + r] = src[(size_t)r * C + cc];
  }
}

// ---------------------------------------------------------------------------
// GRU recurrence for one layer. 32 WGs: {p,q} x {fwd,bwd} x 8 b-groups (Bg=2).
// gi = precomputed x@Wih^T + bih.
//   mode0: gi is [T,B,384] shared by both dirs (bwd reads flipped rows)
//   else : gi is [2,T,B,384] in processing order
//   finalmode: write concat-flip into Hf [T,B,256]; else out [2,T,B,128]
// ---------------------------------------------------------------------------
__global__ __launch_bounds__(256) void gru_rec(
    const float* __restrict__ gi_p, const float* __restrict__ gi_q,
    const float* __restrict__ WhhT,  // [128][384] k-major
    const float* __restrict__ bhh,   // [384]
    float* __restrict__ out_p, float* __restrict__ out_q,
    float* __restrict__ Hp, float* __restrict__ Hq,
    int mode0, int finalmode) {
  int x = blockIdx.x;
  int seq = x >> 4, dir = (x >> 3) & 1, bg = x & 7;
  int T = seq ? QQ : PP;
  const float* gi = seq ? gi_q : gi_p;
  float* out = seq ? out_q : out_p;
  float* Hf  = seq ? Hq   : Hp;
  int b0 = bg * 2;
  int tid = threadIdx.x;
  __shared__ float hs[2][128];
  __shared__ float ghs[2][384];
  ((float*)hs)[tid] = 0.0f;
  __syncthreads();
  int mb = tid / 96, mj = (tid % 96) * 4;  // matvec map (tid<192)
  int gb = tid >> 7, gj = tid & 127;       // gate map
  for (int t = 0; t < T; ++t) {
    if (tid < 192) {  // gh = h @ Whh^T + bhh  (both gates r,z,n: 384 cols)
      float a0 = bhh[mj], a1 = bhh[mj+1], a2 = bhh[mj+2], a3 = bhh[mj+3];
      for (int k = 0; k < 128; ++k) {
        float hv = hs[mb][k];
        float4 wv = *(const float4*)&WhhT[k*384 + mj];
        a0 += hv*wv.x; a1 += hv*wv.y; a2 += hv*wv.z; a3 += hv*wv.w;
      }
      ghs[mb][mj] = a0; ghs[mb][mj+1] = a1; ghs[mb][mj+2] = a2; ghs[mb][mj+3] = a3;
    }
    __syncthreads();
    {
      size_t base;
      if (mode0) {
        int girow = dir ? (T-1-t) : t;
        base = ((size_t)girow*BB + b0+gb)*384;
      } else {
        base = (((size_t)dir*T + t)*BB + b0+gb)*384;
      }
      float gr = gi[base + gj], gz = gi[base + 128 + gj], gn = gi[base + 256 + gj];
      float r = sigm_f(gr + ghs[gb][gj]);
      float z = sigm_f(gz + ghs[gb][128+gj]);
      float n = tanh_f(gn + r * ghs[gb][256+gj]);
      float h2 = (1.0f - z) * n + z * hs[gb][gj];
      hs[gb][gj] = h2;
      if (finalmode) {
        int orow = dir ? (T-1-t) : t;
        Hf[((size_t)orow*BB + b0+gb)*256 + dir*128 + gj] = h2;
      } else {
        out[(((size_t)dir*T + t)*BB + b0+gb)*128 + gj] = h2;
      }
    }
    __syncthreads();
  }
}

// ---------------------------------------------------------------------------
// Gated additive-attention LSTM (match-LSTM / self-matching), both dirs.
// 32 WGs: {fwd,bwd} x 16 batch elements, 512 threads each, T=256 steps.
// Precomputed: attT  = (Hmem@Wmem^T) transposed to [B,128,Qm]
//              Xcur  = Hseq@Wcur^T           [256,B,128]
//              Xg    = Hseq@Wg[:, :256]^T    [256,B,512]
// Per-step state h,c in LDS. Softmax without max-pass (|logit| <= ||watt||_1).
// ---------------------------------------------------------------------------
__global__ __launch_bounds__(512) void attn_rec(
    const float* __restrict__ Hseq,  // [256,16,256]
    const float* __restrict__ Hmem,  // [Qm,16,256]
    const float* __restrict__ attT,  // [16,128,Qm]
    const float* __restrict__ Xcur,  // [256,16,128]
    const float* __restrict__ Xg,    // [256,16,512]
    const float* __restrict__ watt,  // [128]
    const float* __restrict__ WhidT, // [128][128]
    const float* __restrict__ WgwT,  // [256][512]  (Wg[:,256:] transposed)
    const float* __restrict__ WihT,  // [512][512]
    const float* __restrict__ WhhT,  // [128][512]
    const float* __restrict__ bias,  // [512]
    float* __restrict__ Hy,          // [256,16,256]
    int Qm) {
  int dir = blockIdx.x >> 4, b = blockIdx.x & 15;
  int tid = threadIdx.x;
  __shared__ float h[128], c[128], xh[128], pe[256], z[512], zg[512];
  __shared__ float part[2048];
  __shared__ float red[1];
  if (tid < 128) { h[tid] = 0.0f; c[tid] = 0.0f; }
  const int QP  = (Qm == QQ) ? 64 : 256;   // padded mem length (pow2)
  const int HS  = 512 / QP;                // h-slices in score stage
  const int hl  = 128 / HS;
  const int hsh = (Qm == QQ) ? 6 : 8;      // log2(QP)
  __syncthreads();
  for (int t = 0; t < PP; ++t) {
    int row = dir ? (PP-1-t) : t;   // input index AND output index (flip is symmetric)
    if (tid < 128) xh[tid] = Xcur[((size_t)row*BB + b)*128 + tid];
    {  // hW = h @ Whid^T : k-split by 4
      int j = tid & 127, kh = tid >> 7;
      float acc = 0.0f;
      const float* wp = WhidT + j;
      for (int k = kh*32; k < kh*32+32; ++k) acc += h[k] * wp[k*128];
      part[kh*128 + j] = acc;
    }
    __syncthreads();
    if (tid < 128) xh[tid] += part[tid] + part[128+tid] + part[256+tid] + part[384+tid];
    __syncthreads();
    {  // scores: s[q] = sum_h watt[h]*tanh(attT[b,h,q] + xh[h])
      int q = tid & (QP-1), hh = tid >> hsh;
      float acc = 0.0f;
      if (q < Qm) {
        const float* ap = attT + (size_t)b*128*Qm + q;
        for (int h2 = hh*hl; h2 < hh*hl + hl; ++h2)
          acc += watt[h2] * tanh_f(ap[(size_t)h2*Qm] + xh[h2]);
      }
      part[hh*QP + q] = acc;
    }
    __syncthreads();
    if (tid < QP) {
      float s = 0.0f;
      for (int i = 0; i < HS; ++i) s += part[i*QP + tid];
      pe[tid] = (tid < Qm) ? __expf(s) : 0.0f;
    }
    __syncthreads();
    if (tid < 64) {  // sum of exp
      float s2 = 0.0f;
      for (int q2 = tid; q2 < QP; q2 += 64) s2 += pe[q2];
      for (int off = 32; off; off >>= 1) s2 += __shfl_down(s2, off);
      if (tid == 0) red[0] = s2;
    }
    __syncthreads();
    {  // w numerator: sum_q pe[q]*Hmem[q,b,:]  (q-split by 2)
      int d = tid & 255, qh = tid >> 8;
      int half = Qm >> 1;
      float acc = 0.0f;
      for (int q2 = qh*half; q2 < qh*half + half; ++q2)
        acc += pe[q2] * Hmem[((size_t)q2*BB + b)*256 + d];
      part[qh*256 + d] = acc;
    }
    __syncthreads();
    if (tid < 256) {
      z[tid]       = Hseq[((size_t)row*BB + b)*256 + tid];  // x_t
      z[256 + tid] = (part[tid] + part[256+tid]) * fast_rcp(red[0]);  // w
    }
    __syncthreads();
    {  // u = w @ WgwT : k-split by 4, float4 over j
      int jq = tid & 127, kh = tid >> 7;
      float a0=0,a1=0,a2=0,a3=0;
      for (int k = kh*64; k < kh*64+64; ++k) {
        float4 wv = *(const float4*)&WgwT[k*512 + jq*4];
        float zv = z[256+k];
        a0 += zv*wv.x; a1 += zv*wv.y; a2 += zv*wv.z; a3 += zv*wv.w;
      }
      part[kh*512 + jq*4 + 0] = a0; part[kh*512 + jq*4 + 1] = a1;
      part[kh*512 + jq*4 + 2] = a2; part[kh*512 + jq*4 + 3] = a3;
    }
    __syncthreads();
    {  // gated input zg = z * sigmoid(Xg + u)
      float u = part[tid] + part[512+tid] + part[1024+tid] + part[1536+tid];
      float pre = Xg[((size_t)row*BB + b)*512 + tid] + u;
      zg[tid] = z[tid] * sigm_f(pre);
    }
    __syncthreads();
    {  // gates = zg @ Wih^T + h @ Whh^T : k-split by 4
      int jq = tid & 127, kh = tid >> 7;
      float a0=0,a1=0,a2=0,a3=0;
      for (int k = kh*128; k < kh*128+128; ++k) {
        float4 wv = *(const float4*)&WihT[k*512 + jq*4];
        float zv = zg[k];
        a0 += zv*wv.x; a1 += zv*wv.y; a2 += zv*wv.z; a3 += zv*wv.w;
      }
      for (int k = kh*32; k < kh*32+32; ++k) {
        float4 wv = *(const float4*)&WhhT[k*512 + jq*4];
        float hv = h[k];
        a0 += hv*wv.x; a1 += hv*wv.y; a2 += hv*wv.z; a3 += hv*wv.w;
      }
      part[kh*512 + jq*4 + 0] = a0; part[kh*512 + jq*4 + 1] = a1;
      part[kh*512 + jq*4 + 2] = a2; part[kh*512 + jq*4 + 3] = a3;
    }
    __syncthreads();
    if (tid < 128) {  // LSTM cell, gate order i,f,g,o
      float gii = bias[tid]     + part[tid]     + part[512+tid]     + part[1024+tid]     + part[1536+tid];
      float gff = bias[128+tid] + part[128+tid] + part[640+tid]     + part[1152+tid]     + part[1664+tid];
      float ggg = bias[256+tid] + part[256+tid] + part[768+tid]     + part[1280+tid]     + part[1792+tid];
      float goo = bias[384+tid] + part[384+tid] + part[896+tid]     + part[1408+tid]     + part[1920+tid];
      float ii = sigm_f(gii), ff = sigm_f(gff), gg = tanh_f(ggg), oo = sigm_f(goo);
      float cn = ff * c[tid] + ii * gg;
      float hn = oo * tanh_f(cn);
      c[tid] = cn; h[tid] = hn;
      Hy[((size_t)row*BB + b)*256 + dir*128 + tid] = hn;
    }
    __syncthreads();
  }
}

// ---------------------------------------------------------------------------
// Answer pointer network. 16 WGs (one per batch element), 256 threads, 2 steps.
// ---------------------------------------------------------------------------
__global__ __launch_bounds__(256) void ptr_net(
    const float* __restrict__ Hq,    // [48,16,256]
    const float* __restrict__ Hs,    // [256,16,256]
    const float* __restrict__ attp,  // [256,16,128] = Hs@Wal^T
    const float* __restrict__ WaaT,  // [128][128]
    const float* __restrict__ wbeta, // [128]
    const float* __restrict__ WahT,  // [256][128]
    const float* __restrict__ bah,
    const float* __restrict__ WacT,
    const float* __restrict__ bac,
    const float* __restrict__ WihT,  // [256][512]
    const float* __restrict__ WhhT,  // [128][512]
    const float* __restrict__ bptr,  // [512]
    float* __restrict__ out) {       // [2,256,16]
  int b = blockIdx.x;
  int tid = threadIdx.x;
  __shared__ float qp[256], h[128], c[128], haa[128], pe2[256], wv[256], part[1024];
  __shared__ float red[1];
  {  // qp = mean over Q of Hq
    float acc = 0.0f;
    for (int q = 0; q < QQ; ++q) acc += Hq[((size_t)q*BB + b)*256 + tid];
    qp[tid] = acc * (1.0f/48.0f);
  }
  __syncthreads();
  if (tid < 128) {  // init h,c from pooled question
    float ah = bah[tid], ac = bac[tid];
    for (int k = 0; k < 256; ++k) {
      ah += qp[k] * WahT[k*128 + tid];
      ac += qp[k] * WacT[k*128 + tid];
    }
    h[tid] = ah; c[tid] = ac;
  }
  __syncthreads();
  for (int step = 0; step < 2; ++step) {
    if (tid < 128) {
      float acc = 0.0f;
      for (int k = 0; k < 128; ++k) acc += h[k] * WaaT[k*128 + tid];
      haa[tid] = acc;
    }
    __syncthreads();
    {  // beta logits (thread = passage position)
      const float* ap = attp + (size_t)tid*BB*128 + b*128;
      float s = 0.0f;
      for (int k = 0; k < 128; ++k) s += wbeta[k] * tanh_f(ap[k] + haa[k]);
      pe2[tid] = __expf(s);
    }
    __syncthreads();
    if (tid < 64) {
      float s2 = pe2[tid] + pe2[tid+64] + pe2[tid+128] + pe2[tid+192];
      for (int off = 32; off; off >>= 1) s2 += __shfl_down(s2, off);
      if (tid == 0) red[0] = s2;
    }
    __syncthreads();
    float inv = fast_rcp(red[0]);
    out[((size_t)step*PP + tid)*BB + b] = pe2[tid] * inv;  // beta BEFORE cell update
    {
      float acc = 0.0f;
      for (int p2 = 0; p2 < PP; ++p2) acc += pe2[p2] * Hs[((size_t)p2*BB + b)*256 + tid];
      wv[tid] = acc * inv;
    }
    __syncthreads();
    {  // gates = wv @ ptWih^T + h @ ptWhh^T : k-split by 2
      int jq = tid & 127, kh = tid >> 7;
      float a0=0,a1=0,a2=0,a3=0;
      for (int k = kh*128; k < kh*128+128; ++k) {
        float4 w4 = *(const float4*)&WihT[k*512 + jq*4];
        float v = wv[k];
        a0 += v*w4.x; a1 += v*w4.y; a2 += v*w4.z; a3 += v*w4.w;
      }
      for (int k = kh*64; k < kh*64+64; ++k) {
        float4 w4 = *(const float4*)&WhhT[k*512 + jq*4];
        float v = h[k];
        a0 += v*w4.x; a1 += v*w4.y; a2 += v*w4.z; a3 += v*w4.w;
      }
      part[kh*512 + jq*4 + 0] = a0; part[kh*512 + jq*4 + 1] = a1;
      part[kh*512 + jq*4 + 2] = a2; part[kh*512 + jq*4 + 3] = a3;
    }
    __syncthreads();
    if (tid < 128) {
      float gii = bptr[tid]     + part[tid]     + part[512+tid];
      float gff = bptr[128+tid] + part[128+tid] + part[640+tid];
      float ggg = bptr[256+tid] + part[256+tid] + part[768+tid];
      float goo = bptr[384+tid] + part[384+tid] + part[896+tid];
      float ii = sigm_f(gii), ff = sigm_f(gff), gg = tanh_f(ggg), oo = sigm_f(goo);
      float cn = ff * c[tid] + ii * gg;
      h[tid] = oo * tanh_f(cn); c[tid] = cn;
    }
    __syncthreads();
  }
}

// ---------------------------------------------------------------------------
extern "C" void kernel_launch(void* const* d_in, const int* in_sizes, int n_in,
                              void* d_out, int out_size, void* d_ws, size_t ws_size,
                              hipStream_t stream) {
  const float* p_inp  = (const float*)d_in[0];
  const float* q_inp  = (const float*)d_in[1];
  const float* g0_Wih = (const float*)d_in[2];
  const float* g0_Whh = (const float*)d_in[3];
  const float* g0_bih = (const float*)d_in[4];
  const float* g0_bhh = (const float*)d_in[5];
  const float* g1_Wih = (const float*)d_in[6];
  const float* g1_Whh = (const float*)d_in[7];
  const float* g1_bih = (const float*)d_in[8];
  const float* g1_bhh = (const float*)d_in[9];
  const float* g2_Wih = (const float*)d_in[10];
  const float* g2_Whh = (const float*)d_in[11];
  const float* g2_bih = (const float*)d_in[12];
  const float* g2_bhh = (const float*)d_in[13];
  const float* Wq     = (const float*)d_in[14];
  const float* Wp     = (const float*)d_in[15];
  const float* Wh     = (const float*)d_in[16];
  const float* w_alpha= (const float*)d_in[17];
  const float* Wg_m   = (const float*)d_in[18];
  const float* m_Wih  = (const float*)d_in[19];
  const float* m_Whh  = (const float*)d_in[20];
  const float* m_b    = (const float*)d_in[21];
  const float* Wsp    = (const float*)d_in[22];
  const float* Wsh    = (const float*)d_in[23];
  const float* w_gamma= (const float*)d_in[24];
  const float* Wg_s   = (const float*)d_in[25];
  const float* s_Wih  = (const float*)d_in[26];
  const float* s_Whh  = (const float*)d_in[27];
  const float* s_b    = (const float*)d_in[28];
  const float* Wal    = (const float*)d_in[29];
  const float* Waa    = (const float*)d_in[30];
  const float* w_beta = (const float*)d_in[31];
  const float* Wah    = (const float*)d_in[32];
  const float* bah    = (const float*)d_in[33];
  const float* Wac    = (const float*)d_in[34];
  const float* bac    = (const float*)d_in[35];
  const float* pt_Wih = (const float*)d_in[36];
  const float* pt_Whh = (const float*)d_in[37];
  const float* pt_b   = (const float*)d_in[38];

  float* ws = (float*)d_ws;
  size_t o = 0;
  auto alloc = [&](size_t n) { float* p = ws + o; o += n; return p; };
  // transposed weights (k-major for the recurrence matvecs)
  float* g0WhhT = alloc(49152);
  float* g1WhhT = alloc(49152);
  float* g2WhhT = alloc(49152);
  float* WhT    = alloc(16384);
  float* WgmWT  = alloc(131072);
  float* mWihT  = alloc(262144);
  float* mWhhT  = alloc(65536);
  float* WshT   = alloc(16384);
  float* WgsWT  = alloc(131072);
  float* sWihT  = alloc(262144);
  float* sWhhT  = alloc(65536);
  float* WaaT   = alloc(16384);
  float* WahT   = alloc(32768);
  float* WacT   = alloc(32768);
  float* ptWihT = alloc(131072);
  float* ptWhhT = alloc(65536);
  // persistent activations
  float* Hp  = alloc(1048576);   // [256,16,256]
  float* Hq_ = alloc(196608);    // [48,16,256]
  float* Hr  = alloc(1048576);
  float* Hs_ = alloc(1048576);
  // phase-reused region
  float* A = alloc(6225920);
  // GRU views
  float* gi_p = A;                 // [2,256,16,384] (layer0 uses [256,16,384])
  float* gi_q = A + 3145728;       // [2,48,16,384]
  float* hA_p = A + 3735552;       // [2,256,16,128]
  float* hB_p = A + 4784128;
  float* hA_q = A + 5832704;       // [2,48,16,128]
  float* hB_q = A + 6029312;
  // match views
  float* attq  = A;                // [48,16,128]
  float* attqT = A + 98304;        // [16,128,48]
  float* Xp    = A + 196608;       // [256,16,128]
  float* XgM   = A + 720896;       // [256,16,512]
  // self views
  float* attsp  = A;               // [256,16,128]
  float* attspT = A + 524288;      // [16,128,256]
  float* XgS    = A + 1048576;     // [256,16,512]
  // pointer view
  float* attp = A;                 // [256,16,128]

  // 1. weight transposes (one batched launch)
  TDescs tds;
  tds.d[0]  = { g0_Whh, g0WhhT, 384, 128, 128, 0 };
  tds.d[1]  = { g1_Whh, g1WhhT, 384, 128, 128, 0 };
  tds.d[2]  = { g2_Whh, g2WhhT, 384, 128, 128, 0 };
  tds.d[3]  = { Wh,     WhT,    128, 128, 128, 0 };
  tds.d[4]  = { Wg_m,   WgmWT,  512, 256, 512, 256 };
  tds.d[5]  = { m_Wih,  mWihT,  512, 512, 512, 0 };
  tds.d[6]  = { m_Whh,  mWhhT,  512, 128, 128, 0 };
  tds.d[7]  = { Wsh,    WshT,   128, 128, 128, 0 };
  tds.d[8]  = { Wg_s,   WgsWT,  512, 256, 512, 256 };
  tds.d[9]  = { s_Wih,  sWihT,  512, 512, 512, 0 };
  tds.d[10] = { s_Whh,  sWhhT,  512, 128, 128, 0 };
  tds.d[11] = { Waa,    WaaT,   128, 128, 128, 0 };
  tds.d[12] = { Wah,    WahT,   128, 256, 256, 0 };
  tds.d[13] = { Wac,    WacT,   128, 256, 256, 0 };
  tds.d[14] = { pt_Wih, ptWihT, 512, 256, 256, 0 };
  tds.d[15] = { pt_Whh, ptWhhT, 512, 128, 128, 0 };
  transpose_many<<<dim3(1024, 16), 256, 0, stream>>>(tds);

  // 2. GRU encoder (layer0 input GEMMs shared across directions)
  gemm_nt<<<dim3(64, 6),  256, 0, stream>>>(p_inp, 556, g0_Wih, 556, g0_bih, gi_p, 384, 556);
  gemm_nt<<<dim3(12, 6),  256, 0, stream>>>(q_inp, 556, g0_Wih, 556, g0_bih, gi_q, 384, 556);
  gru_rec<<<32, 256, 0, stream>>>(gi_p, gi_q, g0WhhT, g0_bhh, hA_p, hA_q, nullptr, nullptr, 1, 0);
  gemm_nt<<<dim3(128, 6), 256, 0, stream>>>(hA_p, 128, g1_Wih, 128, g1_bih, gi_p, 384, 128);
  gemm_nt<<<dim3(24, 6),  256, 0, stream>>>(hA_q, 128, g1_Wih, 128, g1_bih, gi_q, 384, 128);
  gru_rec<<<32, 256, 0, stream>>>(gi_p, gi_q, g1WhhT, g1_bhh, hB_p, hB_q, nullptr, nullptr, 0, 0);
  gemm_nt<<<dim3(128, 6), 256, 0, stream>>>(hB_p, 128, g2_Wih, 128, g2_bih, gi_p, 384, 128);
  gemm_nt<<<dim3(24, 6),  256, 0, stream>>>(hB_q, 128, g2_Wih, 128, g2_bih, gi_q, 384, 128);
  gru_rec<<<32, 256, 0, stream>>>(gi_p, gi_q, g2WhhT, g2_bhh, hA_p, hA_q, Hp, Hq_, 0, 1);

  // 3. match-LSTM (passage attends over question)
  gemm_nt<<<dim3(12, 2), 256, 0, stream>>>(Hq_, 256, Wq, 256, nullptr, attq, 128, 256);
  transpose_one<<<dim3(384), 256, 0, stream>>>(attq, attqT, 48, 2048);
  gemm_nt<<<dim3(64, 2), 256, 0, stream>>>(Hp, 256, Wp, 256, nullptr, Xp, 128, 256);
  gemm_nt<<<dim3(64, 8), 256, 0, stream>>>(Hp, 256, Wg_m, 512, nullptr, XgM, 512, 256);
  attn_rec<<<32, 512, 0, stream>>>(Hp, Hq_, attqT, Xp, XgM, w_alpha, WhT, WgmWT,
                                   mWihT, mWhhT, m_b, Hr, QQ);

  // 4. self-matching (Wmem == Wcur == Wsp: one projection serves both)
  gemm_nt<<<dim3(64, 2), 256, 0, stream>>>(Hr, 256, Wsp, 256, nullptr, attsp, 128, 256);
  transpose_one<<<dim3(2048), 256, 0, stream>>>(attsp, attspT, 256, 2048);
  gemm_nt<<<dim3(64, 8), 256, 0, stream>>>(Hr, 256, Wg_s, 512, nullptr, XgS, 512, 256);
  attn_rec<<<32, 512, 0, stream>>>(Hr, Hr, attspT, attsp, XgS, w_gamma, WshT, WgsWT,
                                   sWihT, sWhhT, s_b, Hs_, PP);

  // 5. pointer network
  gemm_nt<<<dim3(64, 2), 256, 0, stream>>>(Hs_, 256, Wal, 256, nullptr, attp, 128, 256);
  ptr_net<<<16, 256, 0, stream>>>(Hq_, Hs_, attp, WaaT, w_beta, WahT, bah, WacT, bac,
                                  ptWihT, ptWhhT, pt_b, (float*)d_out);
}

// Round 2
// 17454.216 us; speedup vs baseline: 1.4678x; 1.4678x over previous
//
#include <hip/hip_runtime.h>

// ---------------------------------------------------------------------------
// R-Net forward on MI355X. fp32, round 2: ILP (unrolled, pipelined weight
// loads), deduped weight reads in gru_rec, fewer barriers in attn_rec.
//   P=256 passage len, Q=48 question len, B=16 batch, E=300, H=128
//   D = E+2H = 556, 2H=256, 3H=384, 4H=512
// ---------------------------------------------------------------------------

#define PP 256
#define QQ 48
#define BB 16

__device__ __forceinline__ float fast_rcp(float x) { return __builtin_amdgcn_rcpf(x); }
__device__ __forceinline__ float tanh_f(float x) {
  float e = __expf(2.0f * x);
  return 1.0f - 2.0f * fast_rcp(1.0f + e);
}
__device__ __forceinline__ float sigm_f(float x) {
  return fast_rcp(1.0f + __expf(-x));
}

// ---------------------------------------------------------------------------
// Generic C[M,N] = A[M,K] @ W[N,K]^T + bias.  64x64 tiles, BK=16, 256 thr.
// ---------------------------------------------------------------------------
__global__ __launch_bounds__(256) void gemm_nt(
    const float* __restrict__ A, int lda,
    const float* __restrict__ W, int ldw,
    const float* __restrict__ bias,
    float* __restrict__ C, int ldc, int K) {
  __shared__ float As[64][17];
  __shared__ float Ws[64][17];
  int tid = threadIdx.x;
  int m0 = blockIdx.x * 64, n0 = blockIdx.y * 64;
  int lr = tid >> 2, lq = (tid & 3) * 4;
  int tr = tid >> 4, tc = tid & 15;
  float acc[4][4] = {};
  for (int k0 = 0; k0 < K; k0 += 16) {
    float4 av = {0,0,0,0}, wv = {0,0,0,0};
    if (k0 + lq < K) {
      av = *(const float4*)&A[(size_t)(m0 + lr) * lda + k0 + lq];
      wv = *(const float4*)&W[(size_t)(n0 + lr) * ldw + k0 + lq];
    }
    __syncthreads();
    As[lr][lq+0] = av.x; As[lr][lq+1] = av.y; As[lr][lq+2] = av.z; As[lr][lq+3] = av.w;
    Ws[lr][lq+0] = wv.x; Ws[lr][lq+1] = wv.y; Ws[lr][lq+2] = wv.z; Ws[lr][lq+3] = wv.w;
    __syncthreads();
#pragma unroll
    for (int kk = 0; kk < 16; ++kk) {
      float a4[4], b4[4];
#pragma unroll
      for (int i = 0; i < 4; ++i) a4[i] = As[tr*4+i][kk];
#pragma unroll
      for (int j = 0; j < 4; ++j) b4[j] = Ws[tc*4+j][kk];
#pragma unroll
      for (int i = 0; i < 4; ++i)
#pragma unroll
        for (int j = 0; j < 4; ++j) acc[i][j] += a4[i] * b4[j];
    }
  }
#pragma unroll
  for (int i = 0; i < 4; ++i) {
    int m = m0 + tr*4 + i;
#pragma unroll
    for (int j = 0; j < 4; ++j) {
      int n = n0 + tc*4 + j;
      C[(size_t)m * ldc + n] = acc[i][j] + (bias ? bias[n] : 0.0f);
    }
  }
}

// ---------------------------------------------------------------------------
// Batched weight transposes: dst[c*R + r] = src[r*ld + off + c]
// ---------------------------------------------------------------------------
struct TDesc { const float* src; float* dst; int R, C, ld, off; };
struct TDescs { TDesc d[16]; };

__global__ __launch_bounds__(256) void transpose_many(TDescs ds) {
  TDesc d = ds.d[blockIdx.y];
  int idx = blockIdx.x * 256 + threadIdx.x;
  if (idx < d.R * d.C) {
    int r = idx / d.C, cc = idx % d.C;
    d.dst[(size_t)cc * d.R + r] = d.src[(size_t)r * d.ld + d.off + cc];
  }
}

__global__ __launch_bounds__(256) void transpose_one(
    const float* __restrict__ src, float* __restrict__ dst, int R, int C) {
  int idx = blockIdx.x * 256 + threadIdx.x;
  if (idx < R * C) {
    int r = idx / C, cc = idx % C;
    dst[(size_t)cc * R + r] = src[(size_t)r * C + cc];
  }
}

// ---------------------------------------------------------------------------
// GRU recurrence. 32 WGs: {p,q} x {fwd,bwd} x 8 b-groups (2 batch each).
// Weight float4 loaded ONCE, used for both batch elements; 2-way k-split.
// ---------------------------------------------------------------------------
__global__ __launch_bounds__(256) void gru_rec(
    const float* __restrict__ gi_p, const float* __restrict__ gi_q,
    const float* __restrict__ WhhT,  // [128][384] k-major
    const float* __restrict__ bhh,   // [384]
    float* __restrict__ out_p, float* __restrict__ out_q,
    float* __restrict__ Hp, float* __restrict__ Hq,
    int mode0, int finalmode) {
  int x = blockIdx.x;
  int seq = x >> 4, dir = (x >> 3) & 1, bg = x & 7;
  int T = seq ? QQ : PP;
  const float* gi = seq ? gi_q : gi_p;
  float* out = seq ? out_q : out_p;
  float* Hf  = seq ? Hq   : Hp;
  int b0 = bg * 2;
  int tid = threadIdx.x;
  __shared__ float hs[2][128];
  __shared__ float gpart[2][2][384];   // [ksplit][b][col]
  ((float*)hs)[tid] = 0.0f;
  __syncthreads();
  int ks = tid / 96;            // k-split half (tid<192)
  int jq = (tid % 96) * 4;      // col quad
  int gb = tid >> 7, gj = tid & 127;   // gate map
  for (int t = 0; t < T; ++t) {
    if (tid < 192) {  // partial gh = h @ Whh^T, both batch elements per weight load
      float a0=0,a1=0,a2=0,a3=0, b0a=0,b1a=0,b2a=0,b3a=0;
      const float* wp = WhhT + (size_t)ks*64*384 + jq;
      const float* h0p = &hs[0][ks*64];
      const float* h1p = &hs[1][ks*64];
#pragma unroll 16
      for (int k = 0; k < 64; ++k) {
        float4 wv = *(const float4*)&wp[(size_t)k*384];
        float h0 = h0p[k], h1 = h1p[k];
        a0 += h0*wv.x; a1 += h0*wv.y; a2 += h0*wv.z; a3 += h0*wv.w;
        b0a += h1*wv.x; b1a += h1*wv.y; b2a += h1*wv.z; b3a += h1*wv.w;
      }
      gpart[ks][0][jq+0]=a0;  gpart[ks][0][jq+1]=a1;  gpart[ks][0][jq+2]=a2;  gpart[ks][0][jq+3]=a3;
      gpart[ks][1][jq+0]=b0a; gpart[ks][1][jq+1]=b1a; gpart[ks][1][jq+2]=b2a; gpart[ks][1][jq+3]=b3a;
    }
    __syncthreads();
    {
      size_t base;
      if (mode0) {
        int girow = dir ? (T-1-t) : t;
        base = ((size_t)girow*BB + b0+gb)*384;
      } else {
        base = (((size_t)dir*T + t)*BB + b0+gb)*384;
      }
      float ghr = bhh[gj]     + gpart[0][gb][gj]     + gpart[1][gb][gj];
      float ghz = bhh[128+gj] + gpart[0][gb][128+gj] + gpart[1][gb][128+gj];
      float ghn = bhh[256+gj] + gpart[0][gb][256+gj] + gpart[1][gb][256+gj];
      float gr = gi[base + gj], gz = gi[base + 128 + gj], gn = gi[base + 256 + gj];
      float r = sigm_f(gr + ghr);
      float z = sigm_f(gz + ghz);
      float n = tanh_f(gn + r * ghn);
      float h2 = (1.0f - z) * n + z * hs[gb][gj];
      hs[gb][gj] = h2;
      if (finalmode) {
        int orow = dir ? (T-1-t) : t;
        Hf[((size_t)orow*BB + b0+gb)*256 + dir*128 + gj] = h2;
      } else {
        out[(((size_t)dir*T + t)*BB + b0+gb)*128 + gj] = h2;
      }
    }
    __syncthreads();
  }
}

// ---------------------------------------------------------------------------
// Gated additive-attention LSTM, both dirs. 32 WGs: {fwd,bwd} x 16 batch.
// 512 threads, T=256 steps, 8 barriers/step, all k-loops unrolled/pipelined.
// ---------------------------------------------------------------------------
__global__ __launch_bounds__(512) void attn_rec(
    const float* __restrict__ Hseq,  // [256,16,256]
    const float* __restrict__ Hmem,  // [Qm,16,256]
    const float* __restrict__ attT,  // [16,128,Qm]
    const float* __restrict__ Xcur,  // [256,16,128]
    const float* __restrict__ Xg,    // [256,16,512]
    const float* __restrict__ watt,  // [128]
    const float* __restrict__ WhidT, // [128][128]
    const float* __restrict__ WgwT,  // [256][512]
    const float* __restrict__ WihT,  // [512][512]
    const float* __restrict__ WhhT,  // [128][512]
    const float* __restrict__ bias,  // [512]
    float* __restrict__ Hy,          // [256,16,256]
    int Qm) {
  int dir = blockIdx.x >> 4, b = blockIdx.x & 15;
  int tid = threadIdx.x;
  __shared__ float h[128], c[128], xh[128], wa[128], pe[256], zx[256], zg[512];
  __shared__ float part[2048];
  __shared__ float part2[2048];
  __shared__ float red[1];
  if (tid < 128) { h[tid] = 0.0f; c[tid] = 0.0f; wa[tid] = watt[tid]; }
  const int QP  = (Qm == QQ) ? 64 : 256;   // padded mem length (pow2)
  const int HS  = 512 / QP;                // h-slices in score stage
  const int hl  = 128 / HS;
  const int hsh = (Qm == QQ) ? 6 : 8;      // log2(QP)
  const float* attb = attT + (size_t)b*128*Qm;
  __syncthreads();
  for (int t = 0; t < PP; ++t) {
    int row = dir ? (PP-1-t) : t;
    {  // Stage A: hW partials (k-split 4) + xh / x_t loads
      int j = tid & 127, kh = tid >> 7;
      float acc = 0.0f;
      const float* wp = WhidT + (size_t)kh*32*128 + j;
      const float* hp = &h[kh*32];
#pragma unroll
      for (int k = 0; k < 32; ++k) acc += hp[k] * wp[(size_t)k*128];
      part[kh*128 + j] = acc;
      if (tid < 128) xh[tid] = Xcur[((size_t)row*BB + b)*128 + tid];
      else if (tid < 384) zx[tid-128] = Hseq[((size_t)row*BB + b)*256 + (tid-128)];
    }
    __syncthreads();
    {  // Stage B: scores (fused xh combine): s[q] partial over h-slice
      int q = tid & (QP-1), hh = tid >> hsh;
      float acc = 0.0f;
      if (q < Qm) {
        const float* ap = attb + q;
        int h0 = hh * hl;
#pragma unroll 8
        for (int i = 0; i < hl; ++i) {
          int h2 = h0 + i;
          float xv = xh[h2] + part[h2] + part[128+h2] + part[256+h2] + part[384+h2];
          acc += wa[h2] * tanh_f(ap[(size_t)h2*Qm] + xv);
        }
      }
      part[1024 + hh*QP + q] = acc;
    }
    __syncthreads();
    if (tid < 64) {  // Stage C: combine score partials, exp, sum
      float lsum = 0.0f;
      for (int q2 = tid; q2 < QP; q2 += 64) {
        float s = 0.0f;
#pragma unroll
        for (int i = 0; i < 8; ++i) { if (i < HS) s += part[1024 + i*QP + q2]; }
        float e = (q2 < Qm) ? __expf(s) : 0.0f;
        pe[q2] = e; lsum += e;
      }
#pragma unroll
      for (int off = 32; off; off >>= 1) lsum += __shfl_down(lsum, off);
      if (tid == 0) red[0] = lsum;
    }
    __syncthreads();
    {  // Stage D: w numerator partials (q-split 2)
      int d = tid & 255, qh = tid >> 8;
      int half = Qm >> 1;
      float acc = 0.0f;
      const float* mp = Hmem + ((size_t)(qh*half)*BB + b)*256 + d;
      const float* pp = &pe[qh*half];
#pragma unroll 8
      for (int q2 = 0; q2 < half; ++q2)
        acc += pp[q2] * mp[(size_t)q2*BB*256];
      part[qh*256 + d] = acc;
    }
    __syncthreads();
    {  // Stage E: u = w @ WgwT (k-split 4), fused w combine
      int jq = tid & 127, kh = tid >> 7;
      float invred = fast_rcp(red[0]);
      float a0=0,a1=0,a2=0,a3=0;
      const float* wp = WgwT + (size_t)kh*64*512 + jq*4;
      int k0 = kh*64;
#pragma unroll 8
      for (int k = 0; k < 64; ++k) {
        float wk = (part[k0+k] + part[256+k0+k]) * invred;
        float4 wv = *(const float4*)&wp[(size_t)k*512];
        a0 += wk*wv.x; a1 += wk*wv.y; a2 += wk*wv.z; a3 += wk*wv.w;
      }
      part2[kh*512 + jq*4 + 0] = a0; part2[kh*512 + jq*4 + 1] = a1;
      part2[kh*512 + jq*4 + 2] = a2; part2[kh*512 + jq*4 + 3] = a3;
    }
    __syncthreads();
    {  // Stage F: gated input zg = z * sigmoid(Xg + u); z = [x_t, w]
      float u = part2[tid] + part2[512+tid] + part2[1024+tid] + part2[1536+tid];
      float pre = Xg[((size_t)row*BB + b)*512 + tid] + u;
      float zval = (tid < 256) ? zx[tid]
                               : (part[tid-256] + part[tid]) * fast_rcp(red[0]);
      zg[tid] = zval * sigm_f(pre);
    }
    __syncthreads();
    {  // Stage G: gates = zg @ Wih^T + h @ Whh^T (k-split 4)
      int jq = tid & 127, kh = tid >> 7;
      float a0=0,a1=0,a2=0,a3=0;
      const float* wp = WihT + (size_t)kh*128*512 + jq*4;
      const float* zp = &zg[kh*128];
#pragma unroll 16
      for (int k = 0; k < 128; ++k) {
        float4 wv = *(const float4*)&wp[(size_t)k*512];
        float zv = zp[k];
        a0 += zv*wv.x; a1 += zv*wv.y; a2 += zv*wv.z; a3 += zv*wv.w;
      }
      const float* wp2 = WhhT + (size_t)kh*32*512 + jq*4;
      const float* hp = &h[kh*32];
#pragma unroll
      for (int k = 0; k < 32; ++k) {
        float4 wv = *(const float4*)&wp2[(size_t)k*512];
        float hv = hp[k];
        a0 += hv*wv.x; a1 += hv*wv.y; a2 += hv*wv.z; a3 += hv*wv.w;
      }
      part[kh*512 + jq*4 + 0] = a0; part[kh*512 + jq*4 + 1] = a1;
      part[kh*512 + jq*4 + 2] = a2; part[kh*512 + jq*4 + 3] = a3;
    }
    __syncthreads();
    if (tid < 128) {  // Stage H: LSTM cell (gate order i,f,g,o)
      float gii = bias[tid]     + part[tid]     + part[512+tid]     + part[1024+tid]     + part[1536+tid];
      float gff = bias[128+tid] + part[128+tid] + part[640+tid]     + part[1152+tid]     + part[1664+tid];
      float ggg = bias[256+tid] + part[256+tid] + part[768+tid]     + part[1280+tid]     + part[1792+tid];
      float goo = bias[384+tid] + part[384+tid] + part[896+tid]     + part[1408+tid]     + part[1920+tid];
      float ii = sigm_f(gii), ff = sigm_f(gff), gg = tanh_f(ggg), oo = sigm_f(goo);
      float cn = ff * c[tid] + ii * gg;
      float hn = oo * tanh_f(cn);
      c[tid] = cn; h[tid] = hn;
      Hy[((size_t)row*BB + b)*256 + dir*128 + tid] = hn;
    }
    __syncthreads();
  }
}

// ---------------------------------------------------------------------------
// Answer pointer network. 16 WGs (one per batch element), 256 threads, 2 steps.
// ---------------------------------------------------------------------------
__global__ __launch_bounds__(256) void ptr_net(
    const float* __restrict__ Hq,    // [48,16,256]
    const float* __restrict__ Hs,    // [256,16,256]
    const float* __restrict__ attp,  // [256,16,128] = Hs@Wal^T
    const float* __restrict__ WaaT,  // [128][128]
    const float* __restrict__ wbeta, // [128]
    const float* __restrict__ WahT,  // [256][128]
    const float* __restrict__ bah,
    const float* __restrict__ WacT,
    const float* __restrict__ bac,
    const float* __restrict__ WihT,  // [256][512]
    const float* __restrict__ WhhT,  // [128][512]
    const float* __restrict__ bptr,  // [512]
    float* __restrict__ out) {       // [2,256,16]
  int b = blockIdx.x;
  int tid = threadIdx.x;
  __shared__ float qp[256], h[128], c[128], haa[128], pe2[256], wv[256], part[1024];
  __shared__ float red[1];
  {
    float acc = 0.0f;
#pragma unroll 8
    for (int q = 0; q < QQ; ++q) acc += Hq[((size_t)q*BB + b)*256 + tid];
    qp[tid] = acc * (1.0f/48.0f);
  }
  __syncthreads();
  if (tid < 128) {
    float ah = bah[tid], ac = bac[tid];
#pragma unroll 8
    for (int k = 0; k < 256; ++k) {
      ah += qp[k] * WahT[k*128 + tid];
      ac += qp[k] * WacT[k*128 + tid];
    }
    h[tid] = ah; c[tid] = ac;
  }
  __syncthreads();
  for (int step = 0; step < 2; ++step) {
    if (tid < 128) {
      float acc = 0.0f;
#pragma unroll 8
      for (int k = 0; k < 128; ++k) acc += h[k] * WaaT[k*128 + tid];
      haa[tid] = acc;
    }
    __syncthreads();
    {
      const float* ap = attp + (size_t)tid*BB*128 + b*128;
      float s = 0.0f;
#pragma unroll 8
      for (int k = 0; k < 128; ++k) s += wbeta[k] * tanh_f(ap[k] + haa[k]);
      pe2[tid] = __expf(s);
    }
    __syncthreads();
    if (tid < 64) {
      float s2 = pe2[tid] + pe2[tid+64] + pe2[tid+128] + pe2[tid+192];
#pragma unroll
      for (int off = 32; off; off >>= 1) s2 += __shfl_down(s2, off);
      if (tid == 0) red[0] = s2;
    }
    __syncthreads();
    float inv = fast_rcp(red[0]);
    out[((size_t)step*PP + tid)*BB + b] = pe2[tid] * inv;
    {
      float acc = 0.0f;
#pragma unroll 8
      for (int p2 = 0; p2 < PP; ++p2) acc += pe2[p2] * Hs[((size_t)p2*BB + b)*256 + tid];
      wv[tid] = acc * inv;
    }
    __syncthreads();
    {
      int jq = tid & 127, kh = tid >> 7;
      float a0=0,a1=0,a2=0,a3=0;
      const float* wp = WihT + (size_t)kh*128*512 + jq*4;
      const float* vp = &wv[kh*128];
#pragma unroll 16
      for (int k = 0; k < 128; ++k) {
        float4 w4 = *(const float4*)&wp[(size_t)k*512];
        float v = vp[k];
        a0 += v*w4.x; a1 += v*w4.y; a2 += v*w4.z; a3 += v*w4.w;
      }
      const float* wp2 = WhhT + (size_t)kh*64*512 + jq*4;
      const float* hp = &h[kh*64];
#pragma unroll
      for (int k = 0; k < 64; ++k) {
        float4 w4 = *(const float4*)&wp2[(size_t)k*512];
        float v = hp[k];
        a0 += v*w4.x; a1 += v*w4.y; a2 += v*w4.z; a3 += v*w4.w;
      }
      part[kh*512 + jq*4 + 0] = a0; part[kh*512 + jq*4 + 1] = a1;
      part[kh*512 + jq*4 + 2] = a2; part[kh*512 + jq*4 + 3] = a3;
    }
    __syncthreads();
    if (tid < 128) {
      float gii = bptr[tid]     + part[tid]     + part[512+tid];
      float gff = bptr[128+tid] + part[128+tid] + part[640+tid];
      float ggg = bptr[256+tid] + part[256+tid] + part[768+tid];
      float goo = bptr[384+tid] + part[384+tid] + part[896+tid];
      float ii = sigm_f(gii), ff = sigm_f(gff), gg = tanh_f(ggg), oo = sigm_f(goo);
      float cn = ff * c[tid] + ii * gg;
      h[tid] = oo * tanh_f(cn); c[tid] = cn;
    }
    __syncthreads();
  }
}

// ---------------------------------------------------------------------------
extern "C" void kernel_launch(void* const* d_in, const int* in_sizes, int n_in,
                              void* d_out, int out_size, void* d_ws, size_t ws_size,
                              hipStream_t stream) {
  const float* p_inp  = (const float*)d_in[0];
  const float* q_inp  = (const float*)d_in[1];
  const float* g0_Wih = (const float*)d_in[2];
  const float* g0_Whh = (const float*)d_in[3];
  const float* g0_bih = (const float*)d_in[4];
  const float* g0_bhh = (const float*)d_in[5];
  const float* g1_Wih = (const float*)d_in[6];
  const float* g1_Whh = (const float*)d_in[7];
  const float* g1_bih = (const float*)d_in[8];
  const float* g1_bhh = (const float*)d_in[9];
  const float* g2_Wih = (const float*)d_in[10];
  const float* g2_Whh = (const float*)d_in[11];
  const float* g2_bih = (const float*)d_in[12];
  const float* g2_bhh = (const float*)d_in[13];
  const float* Wq     = (const float*)d_in[14];
  const float* Wp     = (const float*)d_in[15];
  const float* Wh     = (const float*)d_in[16];
  const float* w_alpha= (const float*)d_in[17];
  const float* Wg_m   = (const float*)d_in[18];
  const float* m_Wih  = (const float*)d_in[19];
  const float* m_Whh  = (const float*)d_in[20];
  const float* m_b    = (const float*)d_in[21];
  const float* Wsp    = (const float*)d_in[22];
  const float* Wsh    = (const float*)d_in[23];
  const float* w_gamma= (const float*)d_in[24];
  const float* Wg_s   = (const float*)d_in[25];
  const float* s_Wih  = (const float*)d_in[26];
  const float* s_Whh  = (const float*)d_in[27];
  const float* s_b    = (const float*)d_in[28];
  const float* Wal    = (const float*)d_in[29];
  const float* Waa    = (const float*)d_in[30];
  const float* w_beta = (const float*)d_in[31];
  const float* Wah    = (const float*)d_in[32];
  const float* bah    = (const float*)d_in[33];
  const float* Wac    = (const float*)d_in[34];
  const float* bac    = (const float*)d_in[35];
  const float* pt_Wih = (const float*)d_in[36];
  const float* pt_Whh = (const float*)d_in[37];
  const float* pt_b   = (const float*)d_in[38];

  float* ws = (float*)d_ws;
  size_t o = 0;
  auto alloc = [&](size_t n) { float* p = ws + o; o += n; return p; };
  float* g0WhhT = alloc(49152);
  float* g1WhhT = alloc(49152);
  float* g2WhhT = alloc(49152);
  float* WhT    = alloc(16384);
  float* WgmWT  = alloc(131072);
  float* mWihT  = alloc(262144);
  float* mWhhT  = alloc(65536);
  float* WshT   = alloc(16384);
  float* WgsWT  = alloc(131072);
  float* sWihT  = alloc(262144);
  float* sWhhT  = alloc(65536);
  float* WaaT   = alloc(16384);
  float* WahT   = alloc(32768);
  float* WacT   = alloc(32768);
  float* ptWihT = alloc(131072);
  float* ptWhhT = alloc(65536);
  float* Hp  = alloc(1048576);   // [256,16,256]
  float* Hq_ = alloc(196608);    // [48,16,256]
  float* Hr  = alloc(1048576);
  float* Hs_ = alloc(1048576);
  float* A = alloc(6225920);
  // GRU views
  float* gi_p = A;                 // [2,256,16,384] (layer0 uses [256,16,384])
  float* gi_q = A + 3145728;       // [2,48,16,384]
  float* hA_p = A + 3735552;       // [2,256,16,128]
  float* hB_p = A + 4784128;
  float* hA_q = A + 5832704;       // [2,48,16,128]
  float* hB_q = A + 6029312;
  // match views
  float* attq  = A;                // [48,16,128]
  float* attqT = A + 98304;        // [16,128,48]
  float* Xp    = A + 196608;       // [256,16,128]
  float* XgM   = A + 720896;       // [256,16,512]
  // self views
  float* attsp  = A;               // [256,16,128]
  float* attspT = A + 524288;      // [16,128,256]
  float* XgS    = A + 1048576;     // [256,16,512]
  // pointer view
  float* attp = A;                 // [256,16,128]

  TDescs tds;
  tds.d[0]  = { g0_Whh, g0WhhT, 384, 128, 128, 0 };
  tds.d[1]  = { g1_Whh, g1WhhT, 384, 128, 128, 0 };
  tds.d[2]  = { g2_Whh, g2WhhT, 384, 128, 128, 0 };
  tds.d[3]  = { Wh,     WhT,    128, 128, 128, 0 };
  tds.d[4]  = { Wg_m,   WgmWT,  512, 256, 512, 256 };
  tds.d[5]  = { m_Wih,  mWihT,  512, 512, 512, 0 };
  tds.d[6]  = { m_Whh,  mWhhT,  512, 128, 128, 0 };
  tds.d[7]  = { Wsh,    WshT,   128, 128, 128, 0 };
  tds.d[8]  = { Wg_s,   WgsWT,  512, 256, 512, 256 };
  tds.d[9]  = { s_Wih,  sWihT,  512, 512, 512, 0 };
  tds.d[10] = { s_Whh,  sWhhT,  512, 128, 128, 0 };
  tds.d[11] = { Waa,    WaaT,   128, 128, 128, 0 };
  tds.d[12] = { Wah,    WahT,   128, 256, 256, 0 };
  tds.d[13] = { Wac,    WacT,   128, 256, 256, 0 };
  tds.d[14] = { pt_Wih, ptWihT, 512, 256, 256, 0 };
  tds.d[15] = { pt_Whh, ptWhhT, 512, 128, 128, 0 };
  transpose_many<<<dim3(1024, 16), 256, 0, stream>>>(tds);

  // GRU encoder
  gemm_nt<<<dim3(64, 6),  256, 0, stream>>>(p_inp, 556, g0_Wih, 556, g0_bih, gi_p, 384, 556);
  gemm_nt<<<dim3(12, 6),  256, 0, stream>>>(q_inp, 556, g0_Wih, 556, g0_bih, gi_q, 384, 556);
  gru_rec<<<32, 256, 0, stream>>>(gi_p, gi_q, g0WhhT, g0_bhh, hA_p, hA_q, nullptr, nullptr, 1, 0);
  gemm_nt<<<dim3(128, 6), 256, 0, stream>>>(hA_p, 128, g1_Wih, 128, g1_bih, gi_p, 384, 128);
  gemm_nt<<<dim3(24, 6),  256, 0, stream>>>(hA_q, 128, g1_Wih, 128, g1_bih, gi_q, 384, 128);
  gru_rec<<<32, 256, 0, stream>>>(gi_p, gi_q, g1WhhT, g1_bhh, hB_p, hB_q, nullptr, nullptr, 0, 0);
  gemm_nt<<<dim3(128, 6), 256, 0, stream>>>(hB_p, 128, g2_Wih, 128, g2_bih, gi_p, 384, 128);
  gemm_nt<<<dim3(24, 6),  256, 0, stream>>>(hB_q, 128, g2_Wih, 128, g2_bih, gi_q, 384, 128);
  gru_rec<<<32, 256, 0, stream>>>(gi_p, gi_q, g2WhhT, g2_bhh, hA_p, hA_q, Hp, Hq_, 0, 1);

  // match-LSTM
  gemm_nt<<<dim3(12, 2), 256, 0, stream>>>(Hq_, 256, Wq, 256, nullptr, attq, 128, 256);
  transpose_one<<<dim3(384), 256, 0, stream>>>(attq, attqT, 48, 2048);
  gemm_nt<<<dim3(64, 2), 256, 0, stream>>>(Hp, 256, Wp, 256, nullptr, Xp, 128, 256);
  gemm_nt<<<dim3(64, 8), 256, 0, stream>>>(Hp, 256, Wg_m, 512, nullptr, XgM, 512, 256);
  attn_rec<<<32, 512, 0, stream>>>(Hp, Hq_, attqT, Xp, XgM, w_alpha, WhT, WgmWT,
                                   mWihT, mWhhT, m_b, Hr, QQ);

  // self-matching
  gemm_nt<<<dim3(64, 2), 256, 0, stream>>>(Hr, 256, Wsp, 256, nullptr, attsp, 128, 256);
  transpose_one<<<dim3(2048), 256, 0, stream>>>(attsp, attspT, 256, 2048);
  gemm_nt<<<dim3(64, 8), 256, 0, stream>>>(Hr, 256, Wg_s, 512, nullptr, XgS, 512, 256);
  attn_rec<<<32, 512, 0, stream>>>(Hr, Hr, attspT, attsp, XgS, w_gamma, WshT, WgsWT,
                                   sWihT, sWhhT, s_b, Hs_, PP);

  // pointer network
  gemm_nt<<<dim3(64, 2), 256, 0, stream>>>(Hs_, 256, Wal, 256, nullptr, attp, 128, 256);
  ptr_net<<<16, 256, 0, stream>>>(Hq_, Hs_, attp, WaaT, w_beta, WahT, bah, WacT, bac,
                                  ptWihT, ptWhhT, pt_b, (float*)d_out);
}